// Round 1
// baseline (182.401 us; speedup 1.0000x reference)
//
#include <hip/hip_runtime.h>
#include <math.h>

#define NB  4
#define DD  128
#define HH  128
#define WW  128
#define KS  11
#define PAD 5
#define HT  16   // h-tile for K2

struct GW { float g[KS]; };

// ---------------------------------------------------------------------------
// K1: compute 5 fields (x, y, x^2, y^2, xy) and convolve along W.
// grid.x = NB * Tzp * HH rows, block = 128 (one row per block).
// Writes A[f][n][zl][h][w]; zl indexes local planes, global z = z0 + zl - PAD.
// Out-of-volume z planes are written as zeros (zero padding for the D-conv).
// ---------------------------------------------------------------------------
__global__ __launch_bounds__(128)
void k1_convw(const float* __restrict__ img1, const float* __restrict__ img2,
              float* __restrict__ A, GW gw, int z0, int Tzp) {
    __shared__ float s1[WW + 2 * PAD];
    __shared__ float s2[WW + 2 * PAD];
    const int row = blockIdx.x;
    const int t   = threadIdx.x;
    const int h   = row % HH;
    int rem       = row / HH;
    const int zl  = rem % Tzp;
    const int n   = rem / Tzp;
    const int gz  = z0 + zl - PAD;

    const long long fieldStride = (long long)NB * Tzp * HH * WW;
    const long long outBase = (((long long)(n * Tzp + zl)) * HH + h) * WW + t;

    if (gz < 0 || gz >= DD) {  // zero-pad plane (uniform branch per block)
        #pragma unroll
        for (int f = 0; f < 5; ++f) A[f * fieldStride + outBase] = 0.f;
        return;
    }

    const long long inBase = (((long long)(n * DD + gz)) * HH + h) * WW;
    s1[t + PAD] = img1[inBase + t];
    s2[t + PAD] = img2[inBase + t];
    if (t < PAD) {
        s1[t] = 0.f;               s2[t] = 0.f;
        s1[WW + PAD + t] = 0.f;    s2[WW + PAD + t] = 0.f;
    }
    __syncthreads();

    float a0 = 0.f, a1 = 0.f, a2 = 0.f, a3 = 0.f, a4 = 0.f;
    #pragma unroll
    for (int k = 0; k < KS; ++k) {
        const float g = gw.g[k];
        const float x = s1[t + k];
        const float y = s2[t + k];
        a0 += g * x;
        a1 += g * y;
        a2 += g * x * x;
        a3 += g * y * y;
        a4 += g * x * y;
    }
    A[0 * fieldStride + outBase] = a0;
    A[1 * fieldStride + outBase] = a1;
    A[2 * fieldStride + outBase] = a2;
    A[3 * fieldStride + outBase] = a3;
    A[4 * fieldStride + outBase] = a4;
}

// ---------------------------------------------------------------------------
// K2: convolve along H.  One block per (field, n, zl, h-tile).
// LDS holds (HT+10) x 128 floats; each of 256 threads computes HT*WW/256
// outputs. Zero padding at h edges.
// ---------------------------------------------------------------------------
__global__ __launch_bounds__(256)
void k2_convh(const float* __restrict__ A, float* __restrict__ B,
              GW gw, int Tzp) {
    __shared__ float s[(HT + 2 * PAD) * WW];
    const int b  = blockIdx.x;
    const int t  = threadIdx.x;
    const int ht = b % (HH / HT);
    int rem      = b / (HH / HT);
    const int zl = rem % Tzp;  rem /= Tzp;
    const int n  = rem % NB;
    const int f  = rem / NB;

    const long long fieldStride = (long long)NB * Tzp * HH * WW;
    const long long planeBase = f * fieldStride +
                                ((long long)(n * Tzp + zl)) * (HH * WW);

    for (int l = t; l < (HT + 2 * PAD) * WW; l += 256) {
        const int r = l / WW, w = l % WW;
        const int gh = ht * HT + r - PAD;
        s[l] = (gh >= 0 && gh < HH) ? A[planeBase + (long long)gh * WW + w] : 0.f;
    }
    __syncthreads();

    #pragma unroll
    for (int j = 0; j < (HT * WW) / 256; ++j) {
        const int idx = t + j * 256;
        const int oh = idx / WW, w = idx % WW;
        float acc = 0.f;
        #pragma unroll
        for (int k = 0; k < KS; ++k)
            acc += gw.g[k] * s[(oh + k) * WW + w];
        B[planeBase + (long long)(ht * HT + oh) * WW + w] = acc;
    }
}

// ---------------------------------------------------------------------------
// K3: convolve along D with a rolling 11-register window per field (each B
// voxel read exactly once), fuse SSIM map + partial reduction.
// grid = (NB*HH*WW/256, nChunks); thread owns one (n,h,w) column for `chunk`
// consecutive output planes. All window indices are compile-time constant.
// ---------------------------------------------------------------------------
__global__ __launch_bounds__(256)
void k3_convd_ssim(const float* __restrict__ B, double* __restrict__ partials,
                   GW gw, int Tzp, int chunk, int partialBase) {
    const int t = threadIdx.x;
    const int gidx = blockIdx.x * 256 + t;
    const int w = gidx % WW;
    const int h = (gidx / WW) % HH;
    const int n = gidx / (WW * HH);
    const int p0 = blockIdx.y * chunk;

    const long long fieldStride = (long long)NB * Tzp * HH * WW;
    const long long base0 = (long long)n * Tzp * (HH * WW) + (long long)h * WW + w;

    float win[5][KS];
    #pragma unroll
    for (int f = 0; f < 5; ++f)
        #pragma unroll
        for (int j = 0; j < KS - 1; ++j)
            win[f][j + 1] = B[f * fieldStride + base0 + (long long)(p0 + j) * (HH * WW)];

    const float C1 = 1e-4f, C2 = 9e-4f;
    float sum = 0.f;
    for (int zl = 0; zl < chunk; ++zl) {
        #pragma unroll
        for (int f = 0; f < 5; ++f)
            #pragma unroll
            for (int j = 0; j < KS - 1; ++j)
                win[f][j] = win[f][j + 1];
        const long long poff = (long long)(p0 + zl + KS - 1) * (HH * WW);
        #pragma unroll
        for (int f = 0; f < 5; ++f)
            win[f][KS - 1] = B[f * fieldStride + base0 + poff];

        float acc[5];
        #pragma unroll
        for (int f = 0; f < 5; ++f) {
            float a = 0.f;
            #pragma unroll
            for (int k = 0; k < KS; ++k) a += gw.g[k] * win[f][k];
            acc[f] = a;
        }
        const float mu1 = acc[0], mu2 = acc[1];
        const float mu1s = mu1 * mu1, mu2s = mu2 * mu2, mu12 = mu1 * mu2;
        const float sg1 = acc[2] - mu1s;
        const float sg2 = acc[3] - mu2s;
        const float sg12 = acc[4] - mu12;
        const float num = (2.f * mu12 + C1) * (2.f * sg12 + C2);
        const float den = (mu1s + mu2s + C1) * (sg1 + sg2 + C2);
        sum += num / den;
    }

    __shared__ double red[256];
    red[t] = (double)sum;
    __syncthreads();
    for (int sft = 128; sft > 0; sft >>= 1) {
        if (t < sft) red[t] += red[t + sft];
        __syncthreads();
    }
    if (t == 0)
        partials[partialBase + blockIdx.y * gridDim.x + blockIdx.x] = red[0];
}

// ---------------------------------------------------------------------------
// K4: deterministic final reduce -> mean.
// ---------------------------------------------------------------------------
__global__ __launch_bounds__(256)
void k4_reduce(const double* __restrict__ partials, int nPart,
               float* __restrict__ out) {
    __shared__ double red[256];
    const int t = threadIdx.x;
    double s = 0.0;
    for (int i = t; i < nPart; i += 256) s += partials[i];
    red[t] = s;
    __syncthreads();
    for (int sft = 128; sft > 0; sft >>= 1) {
        if (t < sft) red[t] += red[t + sft];
        __syncthreads();
    }
    if (t == 0) out[0] = (float)(red[0] / (double)(NB * DD * HH * WW));
}

// ---------------------------------------------------------------------------
extern "C" void kernel_launch(void* const* d_in, const int* in_sizes, int n_in,
                              void* d_out, int out_size, void* d_ws, size_t ws_size,
                              hipStream_t stream) {
    const float* img1 = (const float*)d_in[0];
    const float* img2 = (const float*)d_in[1];
    float* out = (float*)d_out;

    GW gw;
    {
        double gs[KS], ssum = 0.0;
        for (int i = 0; i < KS; ++i) {
            const double c = (double)(i - KS / 2);
            gs[i] = exp(-c * c / (2.0 * 1.5 * 1.5));
            ssum += gs[i];
        }
        for (int i = 0; i < KS; ++i) gw.g[i] = (float)(gs[i] / ssum);
    }

    // Pick largest z-slab that fits the workspace.
    int Tz = 128;
    for (;;) {
        const int Tzp = Tz + 2 * PAD;
        const size_t bufElems = 5ull * NB * Tzp * HH * WW;
        const int nSlabs = DD / Tz;
        const int chunk = (Tz < 32) ? Tz : 32;
        const int nChunks = Tz / chunk;
        const size_t nPart = (size_t)nSlabs * nChunks * ((NB * HH * WW) / 256);
        const size_t need = 2ull * bufElems * sizeof(float) + nPart * sizeof(double);
        if (need <= ws_size || Tz <= 8) break;
        Tz >>= 1;
    }

    const int Tzp = Tz + 2 * PAD;
    const size_t bufElems = 5ull * NB * Tzp * HH * WW;
    float* A  = (float*)d_ws;
    float* Bb = A + bufElems;
    double* partials = (double*)(Bb + bufElems);

    const int nSlabs = DD / Tz;
    const int chunk = (Tz < 32) ? Tz : 32;
    const int nChunks = Tz / chunk;
    const int blocksNHW = (NB * HH * WW) / 256;  // 256

    for (int sl = 0; sl < nSlabs; ++sl) {
        const int z0 = sl * Tz;
        k1_convw<<<NB * Tzp * HH, 128, 0, stream>>>(img1, img2, A, gw, z0, Tzp);
        k2_convh<<<5 * NB * Tzp * (HH / HT), 256, 0, stream>>>(A, Bb, gw, Tzp);
        k3_convd_ssim<<<dim3(blocksNHW, nChunks), 256, 0, stream>>>(
            Bb, partials, gw, Tzp, chunk, sl * nChunks * blocksNHW);
    }
    const int nPart = nSlabs * nChunks * blocksNHW;
    k4_reduce<<<1, 256, 0, stream>>>(partials, nPart, out);
}

// Round 2
// 119.996 us; speedup vs baseline: 1.5201x; 1.5201x over previous
//
#include <hip/hip_runtime.h>
#include <math.h>

#define NB  4
#define DD  128
#define HH  128
#define WW  128
#define KS  11
#define PAD 5
#define TH  8                 // output rows per K1 block
#define RR  (TH + 2 * PAD)    // 18 staged W-conved rows
#define CZ  32                // z-chunk length in K2

struct GW { float g[KS]; };

// ---------------------------------------------------------------------------
// K1: fields (x,y,x2,y2,xy) + W-conv + H-conv fused, per (n, z, h-tile).
// Phase W: 576 quad-tasks (18 rows x 32 w-quads); raw inputs read directly
//   from global (L1/L2-cached), 11-tap sliding window over a 20-float register
//   window, results -> LDS s_wc[5][18][128].
// Phase H: thread = (row p in 0..7, quad q); 55 ds_read_b128, 11-tap H-conv,
//   float4 stores to A2[f][n][z][h][w].
// ---------------------------------------------------------------------------
__global__ __launch_bounds__(256)
void k1_conv2d(const float* __restrict__ img1, const float* __restrict__ img2,
               float* __restrict__ A, GW gw) {
    __shared__ float s_wc[5][RR][WW];   // 46,080 B
    const int b  = blockIdx.x;
    const int ht = b & 15;
    const int z  = (b >> 4) & (DD - 1);
    const int n  = b >> 11;
    const int t  = threadIdx.x;
    const int h0 = ht * TH;

    const long long planeBase = ((long long)(n * DD + z)) * (HH * WW);

    // ---- Phase W ----
    for (int task = t; task < RR * 32; task += 256) {
        const int r  = task >> 5;
        const int q  = task & 31;
        const int gh = h0 + r - PAD;

        float a[5][4];
        #pragma unroll
        for (int f = 0; f < 5; ++f) {
            a[f][0] = 0.f; a[f][1] = 0.f; a[f][2] = 0.f; a[f][3] = 0.f;
        }

        if (gh >= 0 && gh < HH) {
            const float* p1 = img1 + planeBase + (long long)gh * WW;
            const float* p2 = img2 + planeBase + (long long)gh * WW;
            float x[20], y[20];
            #pragma unroll
            for (int c = 0; c < 5; ++c) {
                const int w4 = 4 * (q - 2 + c);
                float4 v1 = make_float4(0.f, 0.f, 0.f, 0.f);
                float4 v2 = make_float4(0.f, 0.f, 0.f, 0.f);
                if (w4 >= 0 && w4 < WW) {
                    v1 = *reinterpret_cast<const float4*>(p1 + w4);
                    v2 = *reinterpret_cast<const float4*>(p2 + w4);
                }
                x[4*c+0] = v1.x; x[4*c+1] = v1.y; x[4*c+2] = v1.z; x[4*c+3] = v1.w;
                y[4*c+0] = v2.x; y[4*c+1] = v2.y; y[4*c+2] = v2.z; y[4*c+3] = v2.w;
            }
            #pragma unroll
            for (int k = 0; k < KS; ++k) {
                const float g = gw.g[k];
                #pragma unroll
                for (int j = 0; j < 4; ++j) {
                    const float xv = x[j + k + 3];
                    const float yv = y[j + k + 3];
                    const float gx = g * xv;
                    const float gy = g * yv;
                    a[0][j] += gx;
                    a[1][j] += gy;
                    a[2][j] = fmaf(gx, xv, a[2][j]);
                    a[3][j] = fmaf(gy, yv, a[3][j]);
                    a[4][j] = fmaf(gx, yv, a[4][j]);
                }
            }
        }
        #pragma unroll
        for (int f = 0; f < 5; ++f) {
            *reinterpret_cast<float4*>(&s_wc[f][r][4 * q]) =
                make_float4(a[f][0], a[f][1], a[f][2], a[f][3]);
        }
    }
    __syncthreads();

    // ---- Phase H ----
    const int p = t >> 5;   // local output row 0..7
    const int q = t & 31;   // w-quad
    float4 acc[5];
    #pragma unroll
    for (int f = 0; f < 5; ++f) acc[f] = make_float4(0.f, 0.f, 0.f, 0.f);

    #pragma unroll
    for (int k = 0; k < KS; ++k) {
        const float g = gw.g[k];
        #pragma unroll
        for (int f = 0; f < 5; ++f) {
            const float4 rv =
                *reinterpret_cast<const float4*>(&s_wc[f][p + k][4 * q]);
            acc[f].x = fmaf(g, rv.x, acc[f].x);
            acc[f].y = fmaf(g, rv.y, acc[f].y);
            acc[f].z = fmaf(g, rv.z, acc[f].z);
            acc[f].w = fmaf(g, rv.w, acc[f].w);
        }
    }

    const long long fs = (long long)(5 - 4) * NB * DD * HH * WW;  // per-field stride
    const long long fieldStride = (long long)NB * DD * HH * WW;
    (void)fs;
    const long long ob = planeBase + (long long)(h0 + p) * WW + 4 * q;
    #pragma unroll
    for (int f = 0; f < 5; ++f)
        *reinterpret_cast<float4*>(&A[f * fieldStride + ob]) = acc[f];
}

// ---------------------------------------------------------------------------
// K2: D-conv via register shift-accumulator chain (static indices only),
// fused SSIM + per-block reduction. No LDS except the final reduce buffer.
// Thread owns one (n,h,w) column for a 32-plane z-chunk (10 warm-up steps).
// ---------------------------------------------------------------------------
__global__ __launch_bounds__(256)
void k2_dconv_ssim(const float* __restrict__ A, double* __restrict__ partials,
                   GW gw) {
    const int t  = threadIdx.x;
    const int b  = blockIdx.x;
    const int hb = b & 63;          // 64 h-blocks of 2 rows
    const int zc = (b >> 6) & 3;    // z-chunk
    const int n  = b >> 8;
    const int w  = t & 127;
    const int h  = hb * 2 + (t >> 7);
    const int c0 = zc * CZ;

    const long long fieldStride = (long long)NB * DD * HH * WW;
    const long long colBase =
        (long long)n * DD * HH * WW + (long long)h * WW + w;

    float acc[5][KS];
    #pragma unroll
    for (int f = 0; f < 5; ++f)
        #pragma unroll
        for (int j = 0; j < KS; ++j) acc[f][j] = 0.f;

    const float C1 = 1e-4f, C2 = 9e-4f;
    float sum = 0.f;

    for (int s = 0; s < CZ + 2 * PAD; ++s) {
        const int zi = c0 - PAD + s;
        float v[5];
        if (zi >= 0 && zi < DD) {
            const long long off = colBase + (long long)zi * (HH * WW);
            #pragma unroll
            for (int f = 0; f < 5; ++f) v[f] = A[f * fieldStride + off];
        } else {
            #pragma unroll
            for (int f = 0; f < 5; ++f) v[f] = 0.f;
        }

        #pragma unroll
        for (int f = 0; f < 5; ++f) {
            #pragma unroll
            for (int j = KS - 1; j >= 1; --j)
                acc[f][j] = fmaf(gw.g[j], v[f], acc[f][j - 1]);
            acc[f][0] = gw.g[0] * v[f];
        }

        if (s >= 2 * PAD) {  // acc[f][10] complete for z_out = zi - 5
            const float mu1 = acc[0][KS - 1], mu2 = acc[1][KS - 1];
            const float mu1s = mu1 * mu1, mu2s = mu2 * mu2, mu12 = mu1 * mu2;
            const float sg1  = acc[2][KS - 1] - mu1s;
            const float sg2  = acc[3][KS - 1] - mu2s;
            const float sg12 = acc[4][KS - 1] - mu12;
            const float num = (2.f * mu12 + C1) * (2.f * sg12 + C2);
            const float den = (mu1s + mu2s + C1) * (sg1 + sg2 + C2);
            sum += num / den;
        }
    }

    __shared__ double red[256];
    red[t] = (double)sum;
    __syncthreads();
    for (int sft = 128; sft > 0; sft >>= 1) {
        if (t < sft) red[t] += red[t + sft];
        __syncthreads();
    }
    if (t == 0) partials[b] = red[0];
}

// ---------------------------------------------------------------------------
__global__ __launch_bounds__(256)
void k4_reduce(const double* __restrict__ partials, int nPart,
               float* __restrict__ out) {
    __shared__ double red[256];
    const int t = threadIdx.x;
    double s = 0.0;
    for (int i = t; i < nPart; i += 256) s += partials[i];
    red[t] = s;
    __syncthreads();
    for (int sft = 128; sft > 0; sft >>= 1) {
        if (t < sft) red[t] += red[t + sft];
        __syncthreads();
    }
    if (t == 0) out[0] = (float)(red[0] / (double)((long long)NB * DD * HH * WW));
}

// ---------------------------------------------------------------------------
extern "C" void kernel_launch(void* const* d_in, const int* in_sizes, int n_in,
                              void* d_out, int out_size, void* d_ws, size_t ws_size,
                              hipStream_t stream) {
    const float* img1 = (const float*)d_in[0];
    const float* img2 = (const float*)d_in[1];
    float* out = (float*)d_out;

    GW gw;
    {
        double gs[KS], ssum = 0.0;
        for (int i = 0; i < KS; ++i) {
            const double c = (double)(i - KS / 2);
            gs[i] = exp(-c * c / (2.0 * 1.5 * 1.5));
            ssum += gs[i];
        }
        for (int i = 0; i < KS; ++i) gw.g[i] = (float)(gs[i] / ssum);
    }

    const long long fieldStride = (long long)NB * DD * HH * WW;  // 8,388,608
    float* A = (float*)d_ws;                                     // 5 fields, 168 MB
    double* partials = (double*)(A + 5 * fieldStride);

    const int nBlocksK2 = NB * 4 * 64;  // 1024

    k1_conv2d<<<NB * DD * 16, 256, 0, stream>>>(img1, img2, A, gw);
    k2_dconv_ssim<<<nBlocksK2, 256, 0, stream>>>(A, partials, gw);
    k4_reduce<<<1, 256, 0, stream>>>(partials, nBlocksK2, out);
}